// Round 12
// baseline (224.197 us; speedup 1.0000x reference)
//
#include <hip/hip_runtime.h>
#include <math.h>

namespace {

typedef _Float16 half8 __attribute__((ext_vector_type(8)));
typedef float floatx4 __attribute__((ext_vector_type(4)));

constexpr int kS   = 1024;
constexpr int kD   = 64;
constexpr int kPad = 72;   // 144 B row stride: 16B-aligned (b128-safe)
constexpr float kLog2e = 1.4426950408889634f;
constexpr float kThr   = 8.0f;  // defer-rescale threshold (log2 space)

union H4 { _Float16 h[4]; uint2 u2; };

__device__ __forceinline__ float fast_exp2(float x) {
#if __has_builtin(__builtin_amdgcn_exp2f)
  return __builtin_amdgcn_exp2f(x);
#else
  return exp2f(x);
#endif
}

__device__ __forceinline__ float fast_rcp(float x) {
#if __has_builtin(__builtin_amdgcn_rcpf)
  return __builtin_amdgcn_rcpf(x);
#else
  return 1.0f / x;
#endif
}

// R6 skeleton (best verified 86.5us) with the K LDS round-trip removed:
// K fragments load DIRECTLY from global into MFMA layout (fk[4][2] half8,
// 32 VGPR), one tile ahead. Lane (quad,r) reads K[mt*16+r][ks*32+quad*8..+7]
// (32B contiguous; 4 quads of a row cover 128B). K is L2-resident (256KB/batch
// shared by 4 same-XCD blocks). Deletes sK (-18.4KB LDS), 16 ds_read_b128 and
// 12 staging ops per thread-tile; both QK passes reuse the same regs; QK-A
// starts with zero waits after the barrier. RNE casts unchanged -> math
// identical to R6. SM-B moved before PV-A so S1 dies before the K-load
// transients (register headroom); PV-A+PV-B form one 32-MFMA run that hides
// the L2 latency of the K loads issued just before.
// NOT repeated: 4-wave launch bounds (R2/R7/R8 spill), slim-softmax bundle
// (R11 spill), V swizzle (R9 made read conflicts worse).
__global__ __launch_bounds__(256, 2)
void fa_mfma_kernel(const float* __restrict__ qg, const float* __restrict__ kg,
                    const float* __restrict__ vg, float* __restrict__ og) {
  __shared__ __align__(16) _Float16 sVt[2][64][kPad];  // V^T tiles [buf][d][key]
  __shared__ __align__(16) _Float16 sP [256][kPad];    // P [qrow(block)][key]

  const int tid  = threadIdx.x;
  const int lane = tid & 63;
  const int w    = __builtin_amdgcn_readfirstlane(tid >> 6);
  const int quad = lane >> 4;
  const int r    = lane & 15;

  // XCD swizzle for 512 blocks: batch b's 4 q-tile blocks -> same XCD (i%8).
  const int blk = blockIdx.x;
  const int b     = (blk & 7) + 8 * (blk >> 5);  // batch 0..127
  const int qbase = ((blk >> 3) & 3) * 256;      // q-tile 0..3 (256 rows each)

  const float* qb = qg + (size_t)b * kS * kD;
  const float* kb = kg + (size_t)b * kS * kD;
  const float* vb = vg + (size_t)b * kS * kD;
  float*       ob = og + (size_t)b * kS * kD;

  // ---- Q fragments direct from global: hi/lo f16 split, pre-scaled log2e ----
  half8 fqh[4][2], fql[4][2];  // [ntq][ks]
#pragma unroll
  for (int ntq = 0; ntq < 4; ++ntq)
#pragma unroll
    for (int ks = 0; ks < 2; ++ks) {
      const float* src =
          qb + (size_t)(qbase + w * 64 + ntq * 16 + r) * kD + ks * 32 + quad * 8;
      float4 a = ((const float4*)src)[0];
      float4 c = ((const float4*)src)[1];
      float f[8] = {a.x, a.y, a.z, a.w, c.x, c.y, c.z, c.w};
#pragma unroll
      for (int j = 0; j < 8; ++j) {
        float x = f[j] * kLog2e;
        _Float16 h = (_Float16)x;
        fqh[ntq][ks][j] = h;
        fql[ntq][ks][j] = (_Float16)(x - (float)h);
      }
    }

  float m_i[4] = {-INFINITY, -INFINITY, -INFINITY, -INFINITY};
  float l_i[4] = {0.f, 0.f, 0.f, 0.f};
  floatx4 O[4][4];
#pragma unroll
  for (int a = 0; a < 4; ++a)
#pragma unroll
    for (int c = 0; c < 4; ++c) O[a][c] = floatx4{0.f, 0.f, 0.f, 0.f};

  // ---- K fragments in registers (one tile ahead) ----
  half8 fk[4][2];  // [mt][ks]: K[kt*64 + mt*16 + r][ks*32 + quad*8 ..+7]
  auto load_k = [&](int kt) {
#pragma unroll
    for (int mt = 0; mt < 4; ++mt)
#pragma unroll
      for (int ks = 0; ks < 2; ++ks) {
        const float* s =
            kb + (size_t)(kt * 64 + mt * 16 + r) * kD + ks * 32 + quad * 8;
        float4 a = ((const float4*)s)[0];
        float4 c = ((const float4*)s)[1];
        half8 h;
        h[0] = (_Float16)a.x; h[1] = (_Float16)a.y;
        h[2] = (_Float16)a.z; h[3] = (_Float16)a.w;
        h[4] = (_Float16)c.x; h[5] = (_Float16)c.y;
        h[6] = (_Float16)c.z; h[7] = (_Float16)c.w;
        fk[mt][ks] = h;
      }
  };

  // ---- V prefetch + transpose staging (R6-verbatim) ----
  const int vkey4 = (tid & 15) * 4;   // 4 consecutive keys
  const int vd0   = (tid >> 4) * 4;   // x 4 dims sub-tile
  float4 vbuf[4];
  auto load_v = [&](int kt) {
#pragma unroll
    for (int kk = 0; kk < 4; ++kk)
      vbuf[kk] = *(const float4*)(vb + (size_t)(kt * 64 + vkey4 + kk) * kD + vd0);
  };
  auto stage_v = [&](int bi) {
    float tv[4][4];
#pragma unroll
    for (int kk = 0; kk < 4; ++kk) {
      tv[kk][0] = vbuf[kk].x; tv[kk][1] = vbuf[kk].y;
      tv[kk][2] = vbuf[kk].z; tv[kk][3] = vbuf[kk].w;
    }
#pragma unroll
    for (int j = 0; j < 4; ++j) {
      H4 hv;
#pragma unroll
      for (int kk = 0; kk < 4; ++kk) hv.h[kk] = (_Float16)tv[kk][j];
      *(uint2*)&sVt[bi][vd0 + j][vkey4] = hv.u2;
    }
  };

  // ---- softmax for one pass of 2 q-groups (R6-verbatim + exact tree max) ----
  auto softmax2 = [&](floatx4 (&S)[2][4], int base) {
    float tm[2];
#pragma unroll
    for (int g = 0; g < 2; ++g) {
      float a0 = fmaxf(fmaxf(S[g][0][0], S[g][0][1]), fmaxf(S[g][0][2], S[g][0][3]));
      float a1 = fmaxf(fmaxf(S[g][1][0], S[g][1][1]), fmaxf(S[g][1][2], S[g][1][3]));
      float a2 = fmaxf(fmaxf(S[g][2][0], S[g][2][1]), fmaxf(S[g][2][2], S[g][2][3]));
      float a3 = fmaxf(fmaxf(S[g][3][0], S[g][3][1]), fmaxf(S[g][3][2], S[g][3][3]));
      float t = fmaxf(fmaxf(a0, a1), fmaxf(a2, a3));
      t = fmaxf(t, __shfl_xor(t, 16, 64));
      t = fmaxf(t, __shfl_xor(t, 32, 64));
      tm[g] = t;
    }
    const unsigned long long need =
        __ballot(tm[0] > m_i[base] + kThr || tm[1] > m_i[base + 1] + kThr);
    if (need) {
      float alpha[2];
#pragma unroll
      for (int g = 0; g < 2; ++g) {
        const float mn = fmaxf(m_i[base + g], tm[g]);
        alpha[g] = fast_exp2(m_i[base + g] - mn);  // first tile: exp2(-inf)=0
        m_i[base + g] = mn;
        l_i[base + g] *= alpha[g];
      }
#pragma unroll
      for (int g = 0; g < 2; ++g)
#pragma unroll
        for (int j = 0; j < 4; ++j) {
          const float a = __shfl(alpha[g], quad * 4 + j, 64);
#pragma unroll
          for (int nd = 0; nd < 4; ++nd) O[base + g][nd][j] *= a;
        }
    }
#pragma unroll
    for (int g = 0; g < 2; ++g) {
      float rs = 0.f;
#pragma unroll
      for (int mt = 0; mt < 4; ++mt) {
        H4 hp;
#pragma unroll
        for (int j = 0; j < 4; ++j) {
          float pj = fast_exp2(S[g][mt][j] - m_i[base + g]);
          rs += pj;
          hp.h[j] = (_Float16)pj;
        }
        *(uint2*)&sP[w * 64 + (base + g) * 16 + r][mt * 16 + quad * 4] = hp.u2;
      }
      rs += __shfl_xor(rs, 16, 64);
      rs += __shfl_xor(rs, 32, 64);
      l_i[base + g] += rs;
    }
  };

  // Prologue: fk <- tile 0; sVt buf0 <- tile 0; vbuf <- tile 1.
  load_k(0);
  load_v(0);
  stage_v(0);
  load_v(1);

  for (int kt = 0; kt < kS / 64; ++kt) {
    const int cur = kt & 1, nxt = cur ^ 1;
    __syncthreads();  // sVt[cur] staged & prior reads of sVt[nxt] done
    stage_v(nxt);              // tile kt+1 -> other buffer (overlaps compute)
    load_v((kt + 2) & 15);     // vbuf <- tile kt+2 (wrap harmless)

    // ---- QK pass A (q-groups 0,1): reg-only operands, zero-wait start ----
    floatx4 S0[2][4];
    __builtin_amdgcn_s_setprio(1);
#pragma unroll
    for (int mt = 0; mt < 4; ++mt)
#pragma unroll
      for (int g = 0; g < 2; ++g) {
        floatx4 s = {0.f, 0.f, 0.f, 0.f};
        s = __builtin_amdgcn_mfma_f32_16x16x32_f16(fk[mt][0], fqh[g][0], s, 0, 0, 0);
        s = __builtin_amdgcn_mfma_f32_16x16x32_f16(fk[mt][1], fqh[g][1], s, 0, 0, 0);
        s = __builtin_amdgcn_mfma_f32_16x16x32_f16(fk[mt][0], fql[g][0], s, 0, 0, 0);
        s = __builtin_amdgcn_mfma_f32_16x16x32_f16(fk[mt][1], fql[g][1], s, 0, 0, 0);
        S0[g][mt] = s;
      }
    __builtin_amdgcn_s_setprio(0);

    softmax2(S0, 0);

    // ---- QK pass B (q-groups 2,3): same fk regs ----
    floatx4 S1[2][4];
    __builtin_amdgcn_s_setprio(1);
#pragma unroll
    for (int mt = 0; mt < 4; ++mt)
#pragma unroll
      for (int g = 0; g < 2; ++g) {
        floatx4 s = {0.f, 0.f, 0.f, 0.f};
        s = __builtin_amdgcn_mfma_f32_16x16x32_f16(fk[mt][0], fqh[2 + g][0], s, 0, 0, 0);
        s = __builtin_amdgcn_mfma_f32_16x16x32_f16(fk[mt][1], fqh[2 + g][1], s, 0, 0, 0);
        s = __builtin_amdgcn_mfma_f32_16x16x32_f16(fk[mt][0], fql[2 + g][0], s, 0, 0, 0);
        s = __builtin_amdgcn_mfma_f32_16x16x32_f16(fk[mt][1], fql[2 + g][1], s, 0, 0, 0);
        S1[g][mt] = s;
      }
    __builtin_amdgcn_s_setprio(0);

    softmax2(S1, 2);  // S1 dies here -> register room for the K transients

    // ---- issue next tile's K loads; latency hidden under 32 PV MFMAs ----
    load_k((kt + 1) & 15);

    // ---- PV: O[0..3] in one 32-MFMA run ----
    __builtin_amdgcn_s_setprio(1);
#pragma unroll
    for (int ks = 0; ks < 2; ++ks) {
      half8 fp0 = *(const half8*)&sP[w * 64 + 0 * 16 + r][ks * 32 + quad * 8];
      half8 fp1 = *(const half8*)&sP[w * 64 + 1 * 16 + r][ks * 32 + quad * 8];
      half8 fp2 = *(const half8*)&sP[w * 64 + 2 * 16 + r][ks * 32 + quad * 8];
      half8 fp3 = *(const half8*)&sP[w * 64 + 3 * 16 + r][ks * 32 + quad * 8];
#pragma unroll
      for (int nd = 0; nd < 4; ++nd) {
        half8 fv = *(const half8*)&sVt[cur][nd * 16 + r][ks * 32 + quad * 8];
        O[0][nd] = __builtin_amdgcn_mfma_f32_16x16x32_f16(fp0, fv, O[0][nd], 0, 0, 0);
        O[1][nd] = __builtin_amdgcn_mfma_f32_16x16x32_f16(fp1, fv, O[1][nd], 0, 0, 0);
        O[2][nd] = __builtin_amdgcn_mfma_f32_16x16x32_f16(fp2, fv, O[2][nd], 0, 0, 0);
        O[3][nd] = __builtin_amdgcn_mfma_f32_16x16x32_f16(fp3, fv, O[3][nd], 0, 0, 0);
      }
    }
    __builtin_amdgcn_s_setprio(0);
  }

  // ---- epilogue: out[qrow][dim] = O / l ----
#pragma unroll
  for (int mtq = 0; mtq < 4; ++mtq)
#pragma unroll
    for (int j = 0; j < 4; ++j) {
      const float lrow = __shfl(l_i[mtq], quad * 4 + j, 64);
      const float linv = fast_rcp(lrow);
      float* dst =
          ob + (size_t)(qbase + w * 64 + mtq * 16 + quad * 4 + j) * kD + r;
#pragma unroll
      for (int nd = 0; nd < 4; ++nd) dst[nd * 16] = O[mtq][nd][j] * linv;
    }
}

}  // namespace

extern "C" void kernel_launch(void* const* d_in, const int* in_sizes, int n_in,
                              void* d_out, int out_size, void* d_ws, size_t ws_size,
                              hipStream_t stream) {
  const float* q = (const float*)d_in[0];
  const float* k = (const float*)d_in[1];
  const float* v = (const float*)d_in[2];
  float* out = (float*)d_out;

  fa_mfma_kernel<<<dim3(512), 256, 0, stream>>>(q, k, v, out);
}